// Round 11
// baseline (1168.939 us; speedup 1.0000x reference)
//
#include <hip/hip_runtime.h>
#include <hip/hip_bf16.h>

#define B_   256
#define T_   512
#define H_   128
#define G3_  384

// ---- tiled GEMM config ----
#define TM   128
#define TN   128
#define TK   32
#define LDA  132

__device__ __forceinline__ float sigmoid_f(float x) {
    return 1.0f / (1.0f + __expf(-x));
}
__device__ __forceinline__ float tanh_f(float x) {
    return 1.0f - 2.0f / (__expf(2.0f * x) + 1.0f);
}

// Butterfly sum over each aligned 8-lane group, pure DPP, valid on all lanes.
__device__ __forceinline__ float bfly_fold8(float v) {
    int x;
    x = __builtin_amdgcn_update_dpp(0, __float_as_int(v), 0x0B1, 0xF, 0xF, true);
    v += __int_as_float(x);   // xor 1
    x = __builtin_amdgcn_update_dpp(0, __float_as_int(v), 0x04E, 0xF, 0xF, true);
    v += __int_as_float(x);   // xor 2
    x = __builtin_amdgcn_update_dpp(0, __float_as_int(v), 0x141, 0xF, 0xF, true);
    v += __int_as_float(x);   // half mirror (other quad)
    return v;
}

#define DOT4(acc, hv, wv)                                        \
    acc = fmaf((hv).x, (wv).x, acc);                             \
    acc = fmaf((hv).y, (wv).y, acc);                             \
    acc = fmaf((hv).z, (wv).z, acc);                             \
    acc = fmaf((hv).w, (wv).w, acc);

// volatile 4-float load: cannot be rematerialized -> values must stay in
// registers (or be honestly spilled), never silently re-loaded in-loop.
#define VLD4(dst, base, off) {                                   \
    const volatile float* _p = (base) + (off);                   \
    dst.x = _p[0]; dst.y = _p[1]; dst.z = _p[2]; dst.w = _p[3]; }

#define WROW_DECL(r) float4 w##r##_0, w##r##_1, w##r##_2, w##r##_3;
#define WROW_LOAD(r) {                                           \
    const float* _wr = Whh + (size_t)(j0 + r) * H_ + ks * 16;    \
    VLD4(w##r##_0, _wr, 0)  VLD4(w##r##_1, _wr, 4)               \
    VLD4(w##r##_2, _wr, 8)  VLD4(w##r##_3, _wr, 12) }
#define WROW_DOT(r, p)                                           \
    DOT4(p, hv0, w##r##_0) DOT4(p, hv1, w##r##_1)                \
    DOT4(p, hv2, w##r##_2) DOT4(p, hv3, w##r##_3)

// ---------------------------------------------------------------------------
// gx GEMM (unchanged from R2 — healthy)
// ---------------------------------------------------------------------------
template<bool GATHER>
__global__ __launch_bounds__(256, 2)
void gx_gemm(const float* __restrict__ X,
             const int*   __restrict__ idx,
             const float* __restrict__ emb,
             const float* __restrict__ W,     // [384,128] row-major
             const float* __restrict__ bias,  // [384]
             float*       __restrict__ gx)    // [M,384]
{
    __shared__ __align__(16) float As[2][TK][LDA];
    __shared__ __align__(16) float Bs[2][TK][LDA];

    const int tid = threadIdx.x;
    const int tn  = tid & 15;
    const int tm  = tid >> 4;
    const int n0  = blockIdx.x * TN;
    const int m0  = blockIdx.y * TM;

    const int q  = tid & 7;
    const float* rowA[4];
    const float* rowB[4];
#pragma unroll
    for (int s = 0; s < 4; s++) {
        const int r = (tid >> 3) + 32 * s;
        rowA[s] = GATHER ? (emb + (size_t)idx[m0 + r] * H_)
                         : (X + (size_t)(m0 + r) * H_);
        rowB[s] = W + (size_t)(n0 + r) * H_;
    }

    float4 stA[4], stB[4];
    auto load_chunk = [&](int kc) {
#pragma unroll
        for (int s = 0; s < 4; s++) {
            stA[s] = *(const float4*)(rowA[s] + kc + q * 4);
            stB[s] = *(const float4*)(rowB[s] + kc + q * 4);
        }
    };
    auto store_chunk = [&](int buf) {
#pragma unroll
        for (int s = 0; s < 4; s++) {
            const int r = (tid >> 3) + 32 * s;
#pragma unroll
            for (int d = 0; d < 4; d++) {
                As[buf][q * 4 + d][r] = ((const float*)&stA[s])[d];
                Bs[buf][q * 4 + d][r] = ((const float*)&stB[s])[d];
            }
        }
    };

    float4 acc[2][2][4];
#pragma unroll
    for (int a = 0; a < 2; a++)
#pragma unroll
        for (int b = 0; b < 2; b++)
#pragma unroll
            for (int c = 0; c < 4; c++) acc[a][b][c] = make_float4(0.f, 0.f, 0.f, 0.f);

    load_chunk(0);
    store_chunk(0);
    __syncthreads();

    for (int c = 0; c < 4; c++) {
        if (c < 3) load_chunk((c + 1) * TK);
        const int buf = c & 1;
#pragma unroll 4
        for (int k = 0; k < TK; k++) {
            float4 a0 = *(const float4*)&As[buf][k][tm * 4];
            float4 a1 = *(const float4*)&As[buf][k][64 + tm * 4];
            float4 b0 = *(const float4*)&Bs[buf][k][tn * 4];
            float4 b1 = *(const float4*)&Bs[buf][k][64 + tn * 4];
            float4 av[2] = {a0, a1}, bv[2] = {b0, b1};
#pragma unroll
            for (int mg = 0; mg < 2; mg++)
#pragma unroll
                for (int mi = 0; mi < 4; mi++) {
                    const float am = ((const float*)&av[mg])[mi];
#pragma unroll
                    for (int ng = 0; ng < 2; ng++) {
                        acc[mg][ng][mi].x = fmaf(am, bv[ng].x, acc[mg][ng][mi].x);
                        acc[mg][ng][mi].y = fmaf(am, bv[ng].y, acc[mg][ng][mi].y);
                        acc[mg][ng][mi].z = fmaf(am, bv[ng].z, acc[mg][ng][mi].z);
                        acc[mg][ng][mi].w = fmaf(am, bv[ng].w, acc[mg][ng][mi].w);
                    }
                }
        }
        if (c < 3) {
            store_chunk(buf ^ 1);
            __syncthreads();
        }
    }

    const float4 bb0 = *(const float4*)(bias + n0 + tn * 4);
    const float4 bb1 = *(const float4*)(bias + n0 + 64 + tn * 4);
#pragma unroll
    for (int mg = 0; mg < 2; mg++)
#pragma unroll
        for (int mi = 0; mi < 4; mi++) {
            const int m = m0 + mg * 64 + tm * 4 + mi;
            float* dst = gx + (size_t)m * G3_ + n0;
            float4 v0 = acc[mg][0][mi];
            v0.x += bb0.x; v0.y += bb0.y; v0.z += bb0.z; v0.w += bb0.w;
            float4 v1 = acc[mg][1][mi];
            v1.x += bb1.x; v1.y += bb1.y; v1.z += bb1.z; v1.w += bb1.w;
            *(float4*)(dst + tn * 4) = v0;
            *(float4*)(dst + 64 + tn * 4) = v1;
        }
}

// ---------------------------------------------------------------------------
// GRU recurrence R11: 768 threads (12 waves) per block, one block per batch
// row. Grid = 256 = 1 block/CU -> 12 waves on 4 SIMDs = exactly 3 waves/EU,
// so amdgpu_waves_per_eu(3,3) is truthful -> register budget 512/3 = 170.
// De-templated: R9 (templated, waves_per_eu(4,4)) got VGPR=52 = attribute
// DROPPED; R10 (de-templated, (1,1)) got VGPR=132 = attribute HONORED.
//
// Thread (jg = tid>>3 in [0,96), ks = tid&7): owns W_hh rows 4jg..4jg+3,
// cols ks*16..+15 = 64 fp32 in 16 named volatile-loaded float4s.
// Register need ~106 (64 W + ~42 live) — comfortably under budget, unlike
// R10's 232-vs-132 shortfall.
// Per step: 4 ds_read_b128/thread of swizzled h (8-lane broadcast,
// conflict-free), 64 FMA in 4 chains, 4 DPP folds, ks==0 writes 1 b128 of
// gh; gates on threads 0..127.
//
// h2 swizzle: h[k] at word ((k>>2)&3)*32 + (k>>4)*4 + (k&3)
//   -> read i at words 32i+4ks+{0..3} returns k = 16ks + 4i + c (verified R7).
// ---------------------------------------------------------------------------
__attribute__((amdgpu_flat_work_group_size(768, 768), amdgpu_waves_per_eu(3, 3)))
__global__ void gru_rec(const float* __restrict__ gx,   // [B,T,384]
                        const float* __restrict__ Whh,  // [384,128]
                        const float* __restrict__ bhh,  // [384]
                        float*       __restrict__ hseq, // [B,T,128] if store_h
                        const float* __restrict__ fc_w, // [3,128]  if is_final
                        const float* __restrict__ fc_b, // [3]      if is_final
                        float*       __restrict__ out,  // [B,3]    if is_final
                        int store_h, int is_final)
{
    __shared__ __align__(16) float h2[H_];   // swizzled h
    __shared__ __align__(16) float gh[G3_];

    const int tid = threadIdx.x;
    const int b   = blockIdx.x;
    const int jg  = tid >> 3;      // 0..95
    const int ks  = tid & 7;       // 0..7
    const int j0  = jg * 4;

    // --- W_hh fragment: 16 float4 (64 VGPRs), volatile-loaded ---
    WROW_DECL(0)  WROW_DECL(1)  WROW_DECL(2)  WROW_DECL(3)
    WROW_LOAD(0)  WROW_LOAD(1)  WROW_LOAD(2)  WROW_LOAD(3)

    // --- gate-thread state (tid < 128) ---
    const bool gate = (tid < H_);
    float bhr = 0.f, bhz = 0.f, bhn = 0.f;
    float gr = 0.f, gz = 0.f, gn = 0.f;
    float h_old = 0.f;
    int   hw = 0;
    const float* gxb = gx + (size_t)b * T_ * G3_;
    if (gate) {
        bhr = bhh[tid]; bhz = bhh[tid + H_]; bhn = bhh[tid + 2 * H_];
        gr = gxb[tid]; gz = gxb[tid + H_]; gn = gxb[tid + 2 * H_];
        hw = ((tid >> 2) & 3) * 32 + (tid >> 4) * 4 + (tid & 3);
        h2[tid] = 0.0f;   // zeros are swizzle-invariant
    }
    __syncthreads();

    const int hb = ks * 4;  // base word of this thread's k-slice (swizzled)

    for (int t = 0; t < T_; t++) {
        // prefetch next step's gx (covered by this step's compute)
        float gr2 = 0.f, gz2 = 0.f, gn2 = 0.f;
        if (gate) {
            const float* gnx = gxb + (size_t)min(t + 1, T_ - 1) * G3_;
            gr2 = gnx[tid]; gz2 = gnx[tid + H_]; gn2 = gnx[tid + 2 * H_];
        }

        // ---- phase A: 4 partial dots over this thread's k-slice ----
        const float4 hv0 = *(const float4*)&h2[hb];
        const float4 hv1 = *(const float4*)&h2[32 + hb];
        const float4 hv2 = *(const float4*)&h2[64 + hb];
        const float4 hv3 = *(const float4*)&h2[96 + hb];

        float p0 = 0.f, p1 = 0.f, p2 = 0.f, p3 = 0.f;
        WROW_DOT(0, p0)  WROW_DOT(1, p1)  WROW_DOT(2, p2)  WROW_DOT(3, p3)

        p0 = bfly_fold8(p0);  p1 = bfly_fold8(p1);
        p2 = bfly_fold8(p2);  p3 = bfly_fold8(p3);

        if (ks == 0) {   // 4 contiguous outputs -> 1 coalesced b128 store
            *(float4*)&gh[j0] = make_float4(p0, p1, p2, p3);
        }
        __syncthreads();

        // ---- phase B: gates on threads 0..127 ----
        if (gate) {
            const float ghr = gh[tid] + bhr;
            const float ghz = gh[tid + H_] + bhz;
            const float ghn = gh[tid + 2 * H_] + bhn;
            const float r = sigmoid_f(gr + ghr);
            const float z = sigmoid_f(gz + ghz);
            const float n = tanh_f(gn + r * ghn);
            h_old = (1.0f - z) * n + z * h_old;
            h2[hw] = h_old;
            if (store_h) hseq[((size_t)b * T_ + t) * H_ + tid] = h_old;
            gr = gr2; gz = gz2; gn = gn2;
        }
        __syncthreads();
    }

    if (is_final) {
        if (gate) gh[tid] = fmaxf(h_old, 0.0f);   // relu(last hidden)
        __syncthreads();
        if (tid < 3) {
            float acc = fc_b[tid];
            const float* fw = fc_w + tid * H_;
#pragma unroll
            for (int k = 0; k < H_; k++) acc = fmaf(gh[k], fw[k], acc);
            out[b * 3 + tid] = acc;
        }
    }
}

// ---------------------------------------------------------------------------
extern "C" void kernel_launch(void* const* d_in, const int* in_sizes, int n_in,
                              void* d_out, int out_size, void* d_ws, size_t ws_size,
                              hipStream_t stream)
{
    const int*   x    = (const int*)  d_in[0];
    const float* emb  = (const float*)d_in[1];
    const float* W_ih = (const float*)d_in[2];  // [2,384,128]
    const float* W_hh = (const float*)d_in[3];  // [2,384,128]
    const float* b_ih = (const float*)d_in[4];  // [2,384]
    const float* b_hh = (const float*)d_in[5];  // [2,384]
    const float* fc_w = (const float*)d_in[6];  // [3,128]
    const float* fc_b = (const float*)d_in[7];  // [3]
    float* out = (float*)d_out;

    const int M = B_ * T_;                                   // 131072 rows
    const size_t gx_f32 = (size_t)M * G3_ * sizeof(float);   // 201.3 MB

    float* gx = (float*)d_ws;
    float* h1 = (float*)((char*)d_ws + gx_f32);              // 67.1 MB

    dim3 ggx(G3_ / TN, M / TM);   // (3, 1024)
    dim3 bgx(256);
    dim3 grec(B_), brec(768);

    hipLaunchKernelGGL((gx_gemm<true>), ggx, bgx, 0, stream,
                       nullptr, x, emb, W_ih, b_ih, gx);
    hipLaunchKernelGGL(gru_rec, grec, brec, 0, stream,
                       gx, W_hh, b_hh, h1, nullptr, nullptr, nullptr, 1, 0);
    hipLaunchKernelGGL((gx_gemm<false>), ggx, bgx, 0, stream,
                       h1, nullptr, nullptr, W_ih + G3_ * H_, b_ih + G3_, gx);
    hipLaunchKernelGGL(gru_rec, grec, brec, 0, stream,
                       gx, W_hh + G3_ * H_, b_hh + G3_, nullptr, fc_w, fc_b, out, 0, 1);
}

// Round 12
// 1141.965 us; speedup vs baseline: 1.0236x; 1.0236x over previous
//
#include <hip/hip_runtime.h>
#include <hip/hip_bf16.h>

#define B_   256
#define T_   512
#define H_   128
#define G3_  384

// ---- tiled GEMM config ----
#define TM   128
#define TN   128
#define TK   32
#define LDA  132

__device__ __forceinline__ float sigmoid_f(float x) {
    return 1.0f / (1.0f + __expf(-x));
}
__device__ __forceinline__ float tanh_f(float x) {
    return 1.0f - 2.0f / (__expf(2.0f * x) + 1.0f);
}

// Relaxed workgroup barrier: waits only LDS (lgkmcnt), NOT vmcnt.
// Safe here because all cross-thread data (h2, gh) lives in LDS; the
// in-flight vmem ops (gx prefetch -> private regs, hseq stores -> consumed
// by the NEXT kernel) need no barrier ordering. A plain __syncthreads()
// compiles to s_waitcnt vmcnt(0) lgkmcnt(0); s_barrier — draining the
// ~900-cyc HBM gx prefetch at EVERY step's barrier was ~50% of R11's
// 1833 cyc/step (measured: 862 cyc VALU issue + ~970 stall).
#define REC_BARRIER() __asm__ volatile("s_waitcnt lgkmcnt(0)\n\ts_barrier" ::: "memory")

// Butterfly sum over each aligned 8-lane group, pure DPP, valid on all lanes.
__device__ __forceinline__ float bfly_fold8(float v) {
    int x;
    x = __builtin_amdgcn_update_dpp(0, __float_as_int(v), 0x0B1, 0xF, 0xF, true);
    v += __int_as_float(x);   // xor 1
    x = __builtin_amdgcn_update_dpp(0, __float_as_int(v), 0x04E, 0xF, 0xF, true);
    v += __int_as_float(x);   // xor 2
    x = __builtin_amdgcn_update_dpp(0, __float_as_int(v), 0x141, 0xF, 0xF, true);
    v += __int_as_float(x);   // half mirror (other quad)
    return v;
}

#define DOT4(acc, hv, wv)                                        \
    acc = fmaf((hv).x, (wv).x, acc);                             \
    acc = fmaf((hv).y, (wv).y, acc);                             \
    acc = fmaf((hv).z, (wv).z, acc);                             \
    acc = fmaf((hv).w, (wv).w, acc);

// volatile 4-float load: cannot be rematerialized -> values must stay in
// registers (or be honestly spilled), never silently re-loaded in-loop.
#define VLD4(dst, base, off) {                                   \
    const volatile float* _p = (base) + (off);                   \
    dst.x = _p[0]; dst.y = _p[1]; dst.z = _p[2]; dst.w = _p[3]; }

#define WROW_DECL(r) float4 w##r##_0, w##r##_1, w##r##_2, w##r##_3;
#define WROW_LOAD(r) {                                           \
    const float* _wr = Whh + (size_t)(j0 + r) * H_ + ks * 16;    \
    VLD4(w##r##_0, _wr, 0)  VLD4(w##r##_1, _wr, 4)               \
    VLD4(w##r##_2, _wr, 8)  VLD4(w##r##_3, _wr, 12) }
#define WROW_DOT(r, p)                                           \
    DOT4(p, hv0, w##r##_0) DOT4(p, hv1, w##r##_1)                \
    DOT4(p, hv2, w##r##_2) DOT4(p, hv3, w##r##_3)

// ---------------------------------------------------------------------------
// gx GEMM (unchanged from R2 — healthy)
// ---------------------------------------------------------------------------
template<bool GATHER>
__global__ __launch_bounds__(256, 2)
void gx_gemm(const float* __restrict__ X,
             const int*   __restrict__ idx,
             const float* __restrict__ emb,
             const float* __restrict__ W,     // [384,128] row-major
             const float* __restrict__ bias,  // [384]
             float*       __restrict__ gx)    // [M,384]
{
    __shared__ __align__(16) float As[2][TK][LDA];
    __shared__ __align__(16) float Bs[2][TK][LDA];

    const int tid = threadIdx.x;
    const int tn  = tid & 15;
    const int tm  = tid >> 4;
    const int n0  = blockIdx.x * TN;
    const int m0  = blockIdx.y * TM;

    const int q  = tid & 7;
    const float* rowA[4];
    const float* rowB[4];
#pragma unroll
    for (int s = 0; s < 4; s++) {
        const int r = (tid >> 3) + 32 * s;
        rowA[s] = GATHER ? (emb + (size_t)idx[m0 + r] * H_)
                         : (X + (size_t)(m0 + r) * H_);
        rowB[s] = W + (size_t)(n0 + r) * H_;
    }

    float4 stA[4], stB[4];
    auto load_chunk = [&](int kc) {
#pragma unroll
        for (int s = 0; s < 4; s++) {
            stA[s] = *(const float4*)(rowA[s] + kc + q * 4);
            stB[s] = *(const float4*)(rowB[s] + kc + q * 4);
        }
    };
    auto store_chunk = [&](int buf) {
#pragma unroll
        for (int s = 0; s < 4; s++) {
            const int r = (tid >> 3) + 32 * s;
#pragma unroll
            for (int d = 0; d < 4; d++) {
                As[buf][q * 4 + d][r] = ((const float*)&stA[s])[d];
                Bs[buf][q * 4 + d][r] = ((const float*)&stB[s])[d];
            }
        }
    };

    float4 acc[2][2][4];
#pragma unroll
    for (int a = 0; a < 2; a++)
#pragma unroll
        for (int b = 0; b < 2; b++)
#pragma unroll
            for (int c = 0; c < 4; c++) acc[a][b][c] = make_float4(0.f, 0.f, 0.f, 0.f);

    load_chunk(0);
    store_chunk(0);
    __syncthreads();

    for (int c = 0; c < 4; c++) {
        if (c < 3) load_chunk((c + 1) * TK);
        const int buf = c & 1;
#pragma unroll 4
        for (int k = 0; k < TK; k++) {
            float4 a0 = *(const float4*)&As[buf][k][tm * 4];
            float4 a1 = *(const float4*)&As[buf][k][64 + tm * 4];
            float4 b0 = *(const float4*)&Bs[buf][k][tn * 4];
            float4 b1 = *(const float4*)&Bs[buf][k][64 + tn * 4];
            float4 av[2] = {a0, a1}, bv[2] = {b0, b1};
#pragma unroll
            for (int mg = 0; mg < 2; mg++)
#pragma unroll
                for (int mi = 0; mi < 4; mi++) {
                    const float am = ((const float*)&av[mg])[mi];
#pragma unroll
                    for (int ng = 0; ng < 2; ng++) {
                        acc[mg][ng][mi].x = fmaf(am, bv[ng].x, acc[mg][ng][mi].x);
                        acc[mg][ng][mi].y = fmaf(am, bv[ng].y, acc[mg][ng][mi].y);
                        acc[mg][ng][mi].z = fmaf(am, bv[ng].z, acc[mg][ng][mi].z);
                        acc[mg][ng][mi].w = fmaf(am, bv[ng].w, acc[mg][ng][mi].w);
                    }
                }
        }
        if (c < 3) {
            store_chunk(buf ^ 1);
            __syncthreads();
        }
    }

    const float4 bb0 = *(const float4*)(bias + n0 + tn * 4);
    const float4 bb1 = *(const float4*)(bias + n0 + 64 + tn * 4);
#pragma unroll
    for (int mg = 0; mg < 2; mg++)
#pragma unroll
        for (int mi = 0; mi < 4; mi++) {
            const int m = m0 + mg * 64 + tm * 4 + mi;
            float* dst = gx + (size_t)m * G3_ + n0;
            float4 v0 = acc[mg][0][mi];
            v0.x += bb0.x; v0.y += bb0.y; v0.z += bb0.z; v0.w += bb0.w;
            float4 v1 = acc[mg][1][mi];
            v1.x += bb1.x; v1.y += bb1.y; v1.z += bb1.z; v1.w += bb1.w;
            *(float4*)(dst + tn * 4) = v0;
            *(float4*)(dst + 64 + tn * 4) = v1;
        }
}

// ---------------------------------------------------------------------------
// GRU recurrence R12 = R11 structure + RELAXED in-loop barriers.
// 768 threads (12 waves), one block per batch row (grid=256 = 1 block/CU).
// Thread (jg = tid>>3 in [0,96), ks = tid&7): owns W_hh rows 4jg..4jg+3,
// cols ks*16..+15 = 64 fp32 in 16 named volatile-loaded float4s.
// Per step: 4 ds_read_b128/thread of swizzled h (8-lane broadcast,
// conflict-free), 64 FMA in 4 chains, 4 DPP folds, ks==0 writes 1 b128 of
// gh; gates on threads 0..127; gx prefetched 1 step ahead into registers.
//
// The in-loop barriers wait lgkmcnt only (see REC_BARRIER) — the gx HBM
// prefetch and hseq stores stay in flight across barriers instead of being
// drained every step (R11 measured ~970 cyc/step of non-VALU stall).
//
// h2 swizzle: h[k] at word ((k>>2)&3)*32 + (k>>4)*4 + (k&3)
//   -> read i at words 32i+4ks+{0..3} returns k = 16ks + 4i + c (verified R7).
// ---------------------------------------------------------------------------
__attribute__((amdgpu_flat_work_group_size(768, 768), amdgpu_waves_per_eu(3, 3)))
__global__ void gru_rec(const float* __restrict__ gx,   // [B,T,384]
                        const float* __restrict__ Whh,  // [384,128]
                        const float* __restrict__ bhh,  // [384]
                        float*       __restrict__ hseq, // [B,T,128] if store_h
                        const float* __restrict__ fc_w, // [3,128]  if is_final
                        const float* __restrict__ fc_b, // [3]      if is_final
                        float*       __restrict__ out,  // [B,3]    if is_final
                        int store_h, int is_final)
{
    __shared__ __align__(16) float h2[H_];   // swizzled h
    __shared__ __align__(16) float gh[G3_];

    const int tid = threadIdx.x;
    const int b   = blockIdx.x;
    const int jg  = tid >> 3;      // 0..95
    const int ks  = tid & 7;       // 0..7
    const int j0  = jg * 4;

    // --- W_hh fragment: 16 float4 (64 VGPRs), volatile-loaded ---
    WROW_DECL(0)  WROW_DECL(1)  WROW_DECL(2)  WROW_DECL(3)
    WROW_LOAD(0)  WROW_LOAD(1)  WROW_LOAD(2)  WROW_LOAD(3)

    // --- gate-thread state (tid < 128) ---
    const bool gate = (tid < H_);
    float bhr = 0.f, bhz = 0.f, bhn = 0.f;
    float gr = 0.f, gz = 0.f, gn = 0.f;
    float h_old = 0.f;
    int   hw = 0;
    const float* gxb = gx + (size_t)b * T_ * G3_;
    if (gate) {
        bhr = bhh[tid]; bhz = bhh[tid + H_]; bhn = bhh[tid + 2 * H_];
        gr = gxb[tid]; gz = gxb[tid + H_]; gn = gxb[tid + 2 * H_];
        hw = ((tid >> 2) & 3) * 32 + (tid >> 4) * 4 + (tid & 3);
        h2[tid] = 0.0f;   // zeros are swizzle-invariant
    }
    __syncthreads();   // full barrier once before the loop

    const int hb = ks * 4;  // base word of this thread's k-slice (swizzled)

    for (int t = 0; t < T_; t++) {
        // prefetch next step's gx (stays in flight across relaxed barriers)
        float gr2 = 0.f, gz2 = 0.f, gn2 = 0.f;
        if (gate) {
            const float* gnx = gxb + (size_t)min(t + 1, T_ - 1) * G3_;
            gr2 = gnx[tid]; gz2 = gnx[tid + H_]; gn2 = gnx[tid + 2 * H_];
        }

        // ---- phase A: 4 partial dots over this thread's k-slice ----
        const float4 hv0 = *(const float4*)&h2[hb];
        const float4 hv1 = *(const float4*)&h2[32 + hb];
        const float4 hv2 = *(const float4*)&h2[64 + hb];
        const float4 hv3 = *(const float4*)&h2[96 + hb];

        float p0 = 0.f, p1 = 0.f, p2 = 0.f, p3 = 0.f;
        WROW_DOT(0, p0)  WROW_DOT(1, p1)  WROW_DOT(2, p2)  WROW_DOT(3, p3)

        p0 = bfly_fold8(p0);  p1 = bfly_fold8(p1);
        p2 = bfly_fold8(p2);  p3 = bfly_fold8(p3);

        if (ks == 0) {   // 4 contiguous outputs -> 1 coalesced b128 store
            *(float4*)&gh[j0] = make_float4(p0, p1, p2, p3);
        }
        REC_BARRIER();   // lgkmcnt-only

        // ---- phase B: gates on threads 0..127 ----
        if (gate) {
            const float ghr = gh[tid] + bhr;
            const float ghz = gh[tid + H_] + bhz;
            const float ghn = gh[tid + 2 * H_] + bhn;
            const float r = sigmoid_f(gr + ghr);
            const float z = sigmoid_f(gz + ghz);
            const float n = tanh_f(gn + r * ghn);
            h_old = (1.0f - z) * n + z * h_old;
            h2[hw] = h_old;
            if (store_h) hseq[((size_t)b * T_ + t) * H_ + tid] = h_old;
            gr = gr2; gz = gz2; gn = gn2;
        }
        REC_BARRIER();   // lgkmcnt-only
    }

    if (is_final) {
        __syncthreads();   // full drain before epilogue
        if (gate) gh[tid] = fmaxf(h_old, 0.0f);   // relu(last hidden)
        __syncthreads();
        if (tid < 3) {
            float acc = fc_b[tid];
            const float* fw = fc_w + tid * H_;
#pragma unroll
            for (int k = 0; k < H_; k++) acc = fmaf(gh[k], fw[k], acc);
            out[b * 3 + tid] = acc;
        }
    }
}

// ---------------------------------------------------------------------------
extern "C" void kernel_launch(void* const* d_in, const int* in_sizes, int n_in,
                              void* d_out, int out_size, void* d_ws, size_t ws_size,
                              hipStream_t stream)
{
    const int*   x    = (const int*)  d_in[0];
    const float* emb  = (const float*)d_in[1];
    const float* W_ih = (const float*)d_in[2];  // [2,384,128]
    const float* W_hh = (const float*)d_in[3];  // [2,384,128]
    const float* b_ih = (const float*)d_in[4];  // [2,384]
    const float* b_hh = (const float*)d_in[5];  // [2,384]
    const float* fc_w = (const float*)d_in[6];  // [3,128]
    const float* fc_b = (const float*)d_in[7];  // [3]
    float* out = (float*)d_out;

    const int M = B_ * T_;                                   // 131072 rows
    const size_t gx_f32 = (size_t)M * G3_ * sizeof(float);   // 201.3 MB

    float* gx = (float*)d_ws;
    float* h1 = (float*)((char*)d_ws + gx_f32);              // 67.1 MB

    dim3 ggx(G3_ / TN, M / TM);   // (3, 1024)
    dim3 bgx(256);
    dim3 grec(B_), brec(768);

    hipLaunchKernelGGL((gx_gemm<true>), ggx, bgx, 0, stream,
                       nullptr, x, emb, W_ih, b_ih, gx);
    hipLaunchKernelGGL(gru_rec, grec, brec, 0, stream,
                       gx, W_hh, b_hh, h1, nullptr, nullptr, nullptr, 1, 0);
    hipLaunchKernelGGL((gx_gemm<false>), ggx, bgx, 0, stream,
                       h1, nullptr, nullptr, W_ih + G3_ * H_, b_ih + G3_, gx);
    hipLaunchKernelGGL(gru_rec, grec, brec, 0, stream,
                       gx, W_hh + G3_ * H_, b_hh + G3_, nullptr, fc_w, fc_b, out, 0, 1);
}

// Round 13
// 1114.968 us; speedup vs baseline: 1.0484x; 1.0242x over previous
//
#include <hip/hip_runtime.h>
#include <hip/hip_bf16.h>

#define B_   256
#define T_   512
#define H_   128
#define G3_  384

// ---- tiled GEMM config ----
#define TM   128
#define TN   128
#define TK   32
#define LDA  132

#define NDOT 768   // dot threads (96 jg-groups x 8 ks-lanes)
#define NTHR 896   // + 2 gate waves (threads 768..895 -> j = tid-768 in [0,128))

__device__ __forceinline__ float sigmoid_f(float x) {
    return 1.0f / (1.0f + __expf(-x));
}
__device__ __forceinline__ float tanh_f(float x) {
    return 1.0f - 2.0f / (__expf(2.0f * x) + 1.0f);
}

// Relaxed workgroup barrier: waits LDS ops only (h2/gh are the only
// cross-thread data); gx prefetch loads and hseq stores stay in flight.
#define REC_BARRIER() __asm__ volatile("s_waitcnt lgkmcnt(0)\n\ts_barrier" ::: "memory")

// Butterfly sum over each aligned 8-lane group, pure DPP, valid on all lanes.
__device__ __forceinline__ float bfly_fold8(float v) {
    int x;
    x = __builtin_amdgcn_update_dpp(0, __float_as_int(v), 0x0B1, 0xF, 0xF, true);
    v += __int_as_float(x);   // xor 1
    x = __builtin_amdgcn_update_dpp(0, __float_as_int(v), 0x04E, 0xF, 0xF, true);
    v += __int_as_float(x);   // xor 2
    x = __builtin_amdgcn_update_dpp(0, __float_as_int(v), 0x141, 0xF, 0xF, true);
    v += __int_as_float(x);   // half mirror (other quad)
    return v;
}

#define DOT4(acc, hv, wv)                                        \
    acc = fmaf((hv).x, (wv).x, acc);                             \
    acc = fmaf((hv).y, (wv).y, acc);                             \
    acc = fmaf((hv).z, (wv).z, acc);                             \
    acc = fmaf((hv).w, (wv).w, acc);

// volatile 4-float load: cannot be rematerialized/sunk into the loop.
#define VLD4(dst, base, off) {                                   \
    const volatile float* _p = (base) + (off);                   \
    dst.x = _p[0]; dst.y = _p[1]; dst.z = _p[2]; dst.w = _p[3]; }

#define WROW_DECL(r) float4 w##r##_0, w##r##_1, w##r##_2, w##r##_3;
#define WROW_LOAD(r) {                                           \
    const float* _wr = Whh + (size_t)(j0c + r) * H_ + ks * 16;   \
    VLD4(w##r##_0, _wr, 0)  VLD4(w##r##_1, _wr, 4)               \
    VLD4(w##r##_2, _wr, 8)  VLD4(w##r##_3, _wr, 12) }
#define WROW_DOT(r, p)                                           \
    DOT4(p, hv0, w##r##_0) DOT4(p, hv1, w##r##_1)                \
    DOT4(p, hv2, w##r##_2) DOT4(p, hv3, w##r##_3)

// ---------------------------------------------------------------------------
// gx GEMM (unchanged from R2 — healthy)
// ---------------------------------------------------------------------------
template<bool GATHER>
__global__ __launch_bounds__(256, 2)
void gx_gemm(const float* __restrict__ X,
             const int*   __restrict__ idx,
             const float* __restrict__ emb,
             const float* __restrict__ W,     // [384,128] row-major
             const float* __restrict__ bias,  // [384]
             float*       __restrict__ gx)    // [M,384]
{
    __shared__ __align__(16) float As[2][TK][LDA];
    __shared__ __align__(16) float Bs[2][TK][LDA];

    const int tid = threadIdx.x;
    const int tn  = tid & 15;
    const int tm  = tid >> 4;
    const int n0  = blockIdx.x * TN;
    const int m0  = blockIdx.y * TM;

    const int q  = tid & 7;
    const float* rowA[4];
    const float* rowB[4];
#pragma unroll
    for (int s = 0; s < 4; s++) {
        const int r = (tid >> 3) + 32 * s;
        rowA[s] = GATHER ? (emb + (size_t)idx[m0 + r] * H_)
                         : (X + (size_t)(m0 + r) * H_);
        rowB[s] = W + (size_t)(n0 + r) * H_;
    }

    float4 stA[4], stB[4];
    auto load_chunk = [&](int kc) {
#pragma unroll
        for (int s = 0; s < 4; s++) {
            stA[s] = *(const float4*)(rowA[s] + kc + q * 4);
            stB[s] = *(const float4*)(rowB[s] + kc + q * 4);
        }
    };
    auto store_chunk = [&](int buf) {
#pragma unroll
        for (int s = 0; s < 4; s++) {
            const int r = (tid >> 3) + 32 * s;
#pragma unroll
            for (int d = 0; d < 4; d++) {
                As[buf][q * 4 + d][r] = ((const float*)&stA[s])[d];
                Bs[buf][q * 4 + d][r] = ((const float*)&stB[s])[d];
            }
        }
    };

    float4 acc[2][2][4];
#pragma unroll
    for (int a = 0; a < 2; a++)
#pragma unroll
        for (int b = 0; b < 2; b++)
#pragma unroll
            for (int c = 0; c < 4; c++) acc[a][b][c] = make_float4(0.f, 0.f, 0.f, 0.f);

    load_chunk(0);
    store_chunk(0);
    __syncthreads();

    for (int c = 0; c < 4; c++) {
        if (c < 3) load_chunk((c + 1) * TK);
        const int buf = c & 1;
#pragma unroll 4
        for (int k = 0; k < TK; k++) {
            float4 a0 = *(const float4*)&As[buf][k][tm * 4];
            float4 a1 = *(const float4*)&As[buf][k][64 + tm * 4];
            float4 b0 = *(const float4*)&Bs[buf][k][tn * 4];
            float4 b1 = *(const float4*)&Bs[buf][k][64 + tn * 4];
            float4 av[2] = {a0, a1}, bv[2] = {b0, b1};
#pragma unroll
            for (int mg = 0; mg < 2; mg++)
#pragma unroll
                for (int mi = 0; mi < 4; mi++) {
                    const float am = ((const float*)&av[mg])[mi];
#pragma unroll
                    for (int ng = 0; ng < 2; ng++) {
                        acc[mg][ng][mi].x = fmaf(am, bv[ng].x, acc[mg][ng][mi].x);
                        acc[mg][ng][mi].y = fmaf(am, bv[ng].y, acc[mg][ng][mi].y);
                        acc[mg][ng][mi].z = fmaf(am, bv[ng].z, acc[mg][ng][mi].z);
                        acc[mg][ng][mi].w = fmaf(am, bv[ng].w, acc[mg][ng][mi].w);
                    }
                }
        }
        if (c < 3) {
            store_chunk(buf ^ 1);
            __syncthreads();
        }
    }

    const float4 bb0 = *(const float4*)(bias + n0 + tn * 4);
    const float4 bb1 = *(const float4*)(bias + n0 + 64 + tn * 4);
#pragma unroll
    for (int mg = 0; mg < 2; mg++)
#pragma unroll
        for (int mi = 0; mi < 4; mi++) {
            const int m = m0 + mg * 64 + tm * 4 + mi;
            float* dst = gx + (size_t)m * G3_ + n0;
            float4 v0 = acc[mg][0][mi];
            v0.x += bb0.x; v0.y += bb0.y; v0.z += bb0.z; v0.w += bb0.w;
            float4 v1 = acc[mg][1][mi];
            v1.x += bb1.x; v1.y += bb1.y; v1.z += bb1.z; v1.w += bb1.w;
            *(float4*)(dst + tn * 4) = v0;
            *(float4*)(dst + 64 + tn * 4) = v1;
        }
}

// ---------------------------------------------------------------------------
// GRU recurrence R13: ROLE-SEPARATED block of 896 threads (14 waves), one
// block per batch row (grid=256 = 1 block/CU).
//   threads 0..767  = DOT threads: (jg=tid>>3 in [0,96), ks=tid&7) own W_hh
//                     rows 4jg..4jg+3 x cols 16ks..+15 = 64 fp32 (volatile-
//                     loaded) + ~20 transient regs. NO gate state. Peak ~84
//                     regs -> fits the allocator's stubborn ~84 budget with
//                     NO scratch spill (R11/R12: gate state overlaid on W
//                     threads -> ~99 need -> 15-reg spill reloaded in the
//                     dot's critical path every step = the residual stall).
//   threads 768..895 = GATE threads (2 full waves): j=tid-768 in [0,128).
//                     Hold biases + gx prefetch + h_old (~25 regs, no W).
// Per step: dot waves read 4 swizzled b128 of h (8-lane broadcast), 64 FMA
// in 4 chains, 4 DPP folds, ks==0 writes 1 b128 of gh; gate waves do the
// gate math. Barriers are lgkmcnt-only.
// h2 swizzle: h[k] at word ((k>>2)&3)*32 + (k>>4)*4 + (k&3) (verified R7).
// ---------------------------------------------------------------------------
__attribute__((amdgpu_flat_work_group_size(NTHR, NTHR), amdgpu_waves_per_eu(4, 4)))
__global__ void gru_rec(const float* __restrict__ gx,   // [B,T,384]
                        const float* __restrict__ Whh,  // [384,128]
                        const float* __restrict__ bhh,  // [384]
                        float*       __restrict__ hseq, // [B,T,128] if store_h
                        const float* __restrict__ fc_w, // [3,128]  if is_final
                        const float* __restrict__ fc_b, // [3]      if is_final
                        float*       __restrict__ out,  // [B,3]    if is_final
                        int store_h, int is_final)
{
    __shared__ __align__(16) float h2[H_];   // swizzled h
    __shared__ __align__(16) float gh[G3_];

    const int tid = threadIdx.x;
    const int b   = blockIdx.x;
    const bool dotw = (tid < NDOT);
    const int jg  = tid >> 3;               // 0..111 (only <96 meaningful)
    const int ks  = tid & 7;
    const int j0  = jg * 4;
    const int j0c = min(jg, 95) * 4;        // clamp so gate threads load valid mem

    // --- W_hh fragment: 16 float4 (64 VGPRs), volatile-loaded; gate threads
    //     load a (valid) dummy row and never use it ---
    WROW_DECL(0)  WROW_DECL(1)  WROW_DECL(2)  WROW_DECL(3)
    WROW_LOAD(0)  WROW_LOAD(1)  WROW_LOAD(2)  WROW_LOAD(3)

    // --- gate-thread state (tid >= NDOT): j = tid - NDOT ---
    const int j = tid - NDOT;
    const bool gate = (tid >= NDOT);
    float bhr = 0.f, bhz = 0.f, bhn = 0.f;
    float gr = 0.f, gz = 0.f, gn = 0.f;
    float h_old = 0.f;
    int   hw = 0;
    const float* gxb = gx + (size_t)b * T_ * G3_;
    if (gate) {
        bhr = bhh[j]; bhz = bhh[j + H_]; bhn = bhh[j + 2 * H_];
        gr = gxb[j]; gz = gxb[j + H_]; gn = gxb[j + 2 * H_];
        hw = ((j >> 2) & 3) * 32 + (j >> 4) * 4 + (j & 3);
        h2[j] = 0.0f;   // zeros are swizzle-invariant
    }
    __syncthreads();   // full barrier once before the loop

    const int hb = ks * 4;  // base word of this thread's k-slice (swizzled)

    for (int t = 0; t < T_; t++) {
        if (gate) {
            // prefetch next step's gx (stays in flight across barriers)
            const float* gnx = gxb + (size_t)min(t + 1, T_ - 1) * G3_;
            const float gr2 = gnx[j], gz2 = gnx[j + H_], gn2 = gnx[j + 2 * H_];

            REC_BARRIER();   // wait for dot waves' gh writes (phase A)

            const float ghr = gh[j] + bhr;
            const float ghz = gh[j + H_] + bhz;
            const float ghn = gh[j + 2 * H_] + bhn;
            const float r = sigmoid_f(gr + ghr);
            const float z = sigmoid_f(gz + ghz);
            const float n = tanh_f(gn + r * ghn);
            h_old = (1.0f - z) * n + z * h_old;
            h2[hw] = h_old;
            if (store_h) hseq[((size_t)b * T_ + t) * H_ + j] = h_old;
            gr = gr2; gz = gz2; gn = gn2;

            REC_BARRIER();   // h2 visible before dot waves' next read
        } else {
            // ---- phase A: 4 partial dots over this thread's k-slice ----
            const float4 hv0 = *(const float4*)&h2[hb];
            const float4 hv1 = *(const float4*)&h2[32 + hb];
            const float4 hv2 = *(const float4*)&h2[64 + hb];
            const float4 hv3 = *(const float4*)&h2[96 + hb];

            float p0 = 0.f, p1 = 0.f, p2 = 0.f, p3 = 0.f;
            WROW_DOT(0, p0)  WROW_DOT(1, p1)  WROW_DOT(2, p2)  WROW_DOT(3, p3)

            p0 = bfly_fold8(p0);  p1 = bfly_fold8(p1);
            p2 = bfly_fold8(p2);  p3 = bfly_fold8(p3);

            if (ks == 0) {   // 1 coalesced b128 store of 4 contiguous outputs
                *(float4*)&gh[j0] = make_float4(p0, p1, p2, p3);
            }
            REC_BARRIER();   // gh ready for gate waves
            REC_BARRIER();   // gate waves' h2 write done
        }
    }

    if (is_final) {
        __syncthreads();
        if (gate) gh[j] = fmaxf(h_old, 0.0f);   // relu(last hidden)
        __syncthreads();
        if (tid < 3) {
            float acc = fc_b[tid];
            const float* fw = fc_w + tid * H_;
#pragma unroll
            for (int k = 0; k < H_; k++) acc = fmaf(gh[k], fw[k], acc);
            out[b * 3 + tid] = acc;
        }
    }
}

// ---------------------------------------------------------------------------
extern "C" void kernel_launch(void* const* d_in, const int* in_sizes, int n_in,
                              void* d_out, int out_size, void* d_ws, size_t ws_size,
                              hipStream_t stream)
{
    const int*   x    = (const int*)  d_in[0];
    const float* emb  = (const float*)d_in[1];
    const float* W_ih = (const float*)d_in[2];  // [2,384,128]
    const float* W_hh = (const float*)d_in[3];  // [2,384,128]
    const float* b_ih = (const float*)d_in[4];  // [2,384]
    const float* b_hh = (const float*)d_in[5];  // [2,384]
    const float* fc_w = (const float*)d_in[6];  // [3,128]
    const float* fc_b = (const float*)d_in[7];  // [3]
    float* out = (float*)d_out;

    const int M = B_ * T_;                                   // 131072 rows
    const size_t gx_f32 = (size_t)M * G3_ * sizeof(float);   // 201.3 MB

    float* gx = (float*)d_ws;
    float* h1 = (float*)((char*)d_ws + gx_f32);              // 67.1 MB

    dim3 ggx(G3_ / TN, M / TM);   // (3, 1024)
    dim3 bgx(256);
    dim3 grec(B_), brec(NTHR);

    hipLaunchKernelGGL((gx_gemm<true>), ggx, bgx, 0, stream,
                       nullptr, x, emb, W_ih, b_ih, gx);
    hipLaunchKernelGGL(gru_rec, grec, brec, 0, stream,
                       gx, W_hh, b_hh, h1, nullptr, nullptr, nullptr, 1, 0);
    hipLaunchKernelGGL((gx_gemm<false>), ggx, bgx, 0, stream,
                       h1, nullptr, nullptr, W_ih + G3_ * H_, b_ih + G3_, gx);
    hipLaunchKernelGGL(gru_rec, grec, brec, 0, stream,
                       gx, W_hh + G3_ * H_, b_hh + G3_, nullptr, fc_w, fc_b, out, 0, 1);
}